// Round 7
// baseline (257.104 us; speedup 1.0000x reference)
//
#include <hip/hip_runtime.h>
#include <hip/hip_bf16.h>

typedef __attribute__((ext_vector_type(8))) short s16x8;
typedef __attribute__((ext_vector_type(16))) float f32x16;

#define MOD_SCALE 0.014731391274719739f  // 1/sqrt(512*9)

__device__ __forceinline__ void gload_lds16(const void* g, void* l) {
    __builtin_amdgcn_global_load_lds(
        (const __attribute__((address_space(1))) unsigned int*)g,
        (__attribute__((address_space(3))) unsigned int*)l, 16, 0, 0);
}

// Full drain + barrier (R9 semantics, proven).
__device__ __forceinline__ void sync_drain() {
    __builtin_amdgcn_s_waitcnt(0);
    __syncthreads();
}

// ---------------------------------------------------------------------------
// xs layout (channel-blocked, proven): [b][cb=16][row=66][col=66][32ci*2B]
//   b stride 4,460,544 B; cb stride 278,784 B; entry stride 64 B.
//
// R13: k_prep SPLIT into k_xprep + k_aux so rocprof reports each duration
// (the ~117 us residual was invariant to code shape AND occupancy across
// R7..R12 -> need direct observation). k_xprep also rewritten to stream x
// in 1-KB CONTIGUOUS segments (was 256-B segments @ 16-KB stride in every
// prior variant -> suspected HBM-pattern bound):
//   block = (b, hq, cie): 8 x 16 x 8 = 1024 blocks; 64 ci x 4 h x 64 w.
//   read: per ci, x[b][ci][h0:h0+4][0:64] = 1024 B contiguous (wave = one
//         ci, 64 float4 lanes). write: per (cb,hr) round, wave stores
//         uint4 lanes covering 1 KB contiguous xs.
//   LDS tile [64][258] bf16 (row 516 B): gather instr banks =
//         (8*cig + j + w/2)%32 -> 32 banks, 2 same-dword lanes/bank (free).
// ---------------------------------------------------------------------------
__global__ __launch_bounds__(256) void k_xprep(const float* __restrict__ x,
                                               const float* __restrict__ style,
                                               __hip_bfloat16* __restrict__ xs) {
    __shared__ __align__(16) char sm[33280];  // 33,024 tile + 256 sf
    const int t = threadIdx.x;
    const int bid = blockIdx.x;
    const int b = bid >> 7;
    const int r = bid & 127;
    const int hq = r >> 3, cie = r & 7;
    const int ci0 = cie * 64, h0 = hq * 4;

    __hip_bfloat16 (*tile)[258] = (__hip_bfloat16(*)[258])sm;
    float* sf = (float*)(sm + 33024);
    if (t < 64) sf[t] = style[b * 512 + ci0 + t] * MOD_SCALE;
    __syncthreads();

    // ---- load: 64 ci x 256 sp floats; wave = one ci row, 1 KB contiguous ----
    const float* xb = x + ((size_t)(b * 512 + ci0) * 64 + h0) * 64;
#pragma unroll 4
    for (int it = 0; it < 16; ++it) {
        int idx = it * 256 + t;
        int ci = idx >> 6, c4 = idx & 63;
        float4 v = *(const float4*)(xb + (size_t)ci * 4096 + c4 * 4);
        float s = sf[ci];
        union { unsigned u[2]; __hip_bfloat16 q[4]; } pk;
        pk.q[0] = __float2bfloat16(v.x * s);
        pk.q[1] = __float2bfloat16(v.y * s);
        pk.q[2] = __float2bfloat16(v.z * s);
        pk.q[3] = __float2bfloat16(v.w * s);
        char* d = (char*)sm + ci * 516 + c4 * 8;  // 4-aligned (516 = 4*129)
        *(unsigned*)d = pk.u[0];
        *(unsigned*)(d + 4) = pk.u[1];
    }
    __syncthreads();

    // ---- gather + store: per (cbL,hr) round, wave = 1 KB contiguous ----
    const int cig = t & 3, w = t >> 2;   // w in [0,64)
    char* xsb = (char*)xs + (size_t)b * 4460544;
#pragma unroll
    for (int cbL = 0; cbL < 2; ++cbL) {
        const size_t cbo = (size_t)(cie * 2 + cbL) * 278784;
#pragma unroll
        for (int hr = 0; hr < 4; ++hr) {
            const int sp = hr * 64 + w;
            union { uint4 u; __hip_bfloat16 q[8]; } pk;
#pragma unroll
            for (int j = 0; j < 8; ++j)
                pk.q[j] = tile[cbL * 32 + cig * 8 + j][sp];
            *(uint4*)(xsb + cbo +
                      (size_t)((h0 + hr + 1) * 66 + (w + 1)) * 64 +
                      cig * 16) = pk.u;
        }
    }
}

// ---------------------------------------------------------------------------
// k_aux: border zero + wprep + demod (identical formulas, proven).
//   [0,520) border | [520,1544) wprep | [1544,2056) demod
// ---------------------------------------------------------------------------
__global__ __launch_bounds__(256) void k_aux(const float* __restrict__ style,
                                             const float* __restrict__ weight,
                                             __hip_bfloat16* __restrict__ xs,
                                             __hip_bfloat16* __restrict__ wb,
                                             float* __restrict__ dem) {
    __shared__ __align__(16) char sm[16896];
    const int t = threadIdx.x;
    const int bid = blockIdx.x;

    if (bid < 520) {
        const int idx = bid * 256 + t;
        const int b = idx / 16640;
        const int r2 = idx - b * 16640;
        const int cb = r2 / 1040;
        const int r3 = r2 - cb * 1040;
        const int pair = r3 >> 2;
        const int chunk = r3 & 3;
        int pr, pc;
        if (pair < 66)       { pr = 0;          pc = pair; }
        else if (pair < 132) { pr = 65;         pc = pair - 66; }
        else if (pair < 196) { pr = pair - 131; pc = 0; }
        else                 { pr = pair - 195; pc = 65; }
        char* d = (char*)xs +
                  ((size_t)(b * 16 + cb) * 4356 + pr * 66 + pc) * 64 +
                  chunk * 16;
        *(uint4*)d = make_uint4(0u, 0u, 0u, 0u);
    } else if (bid < 1544) {
        const int r = bid - 520;
        float* lds = (float*)sm;
        const int p0 = r * 256;
        const float* src = weight + (size_t)p0 * 9;
#pragma unroll
        for (int k = 0; k < 9; ++k) lds[k * 256 + t] = src[k * 256 + t];
        __syncthreads();
#pragma unroll
        for (int tap = 0; tap < 9; ++tap)
            wb[(size_t)tap * 262144 + p0 + t] = __float2bfloat16(lds[t * 9 + tap]);
    } else {
        const int co = bid - 1544;
        float* s2 = (float*)sm;
        for (int i = t; i < 4096; i += 256) { float v = style[i]; s2[i] = v * v; }
        __syncthreads();
        const float4* wp = (const float4*)(weight + (size_t)co * 4608);
        float acc[8] = {0.f, 0.f, 0.f, 0.f, 0.f, 0.f, 0.f, 0.f};
        for (int j = t; j < 1152; j += 256) {
            float4 v = wp[j];
            float w2[4] = {v.x * v.x, v.y * v.y, v.z * v.z, v.w * v.w};
            int base = j * 4;
#pragma unroll
            for (int e = 0; e < 4; ++e) {
                int ci = (base + e) / 9;
                float ww = w2[e];
#pragma unroll
                for (int bb = 0; bb < 8; ++bb) acc[bb] += ww * s2[bb * 512 + ci];
            }
        }
#pragma unroll
        for (int bb = 0; bb < 8; ++bb)
            for (int off = 32; off > 0; off >>= 1)
                acc[bb] += __shfl_down(acc[bb], off);
        float* red = (float*)(sm + 16384);
        const int wv = t >> 6, lane = t & 63;
        if (lane == 0) {
#pragma unroll
            for (int bb = 0; bb < 8; ++bb) red[wv * 8 + bb] = acc[bb];
        }
        __syncthreads();
        if (t < 8) {
            float s = red[t] + red[8 + t] + red[16 + t] + red[24 + t];
            const float S2 = MOD_SCALE * MOD_SCALE;
            dem[t * 512 + co] = rsqrtf(S2 * s + 1e-8f);
        }
    }
}

// ---------------------------------------------------------------------------
// Conv: EXACT R11/R12 body (proven ~133.6 us). Untouched this round.
// ---------------------------------------------------------------------------
__global__ __launch_bounds__(256, 2) void k_conv(
    const __hip_bfloat16* __restrict__ xs,   // [b][16][66][66][64B] blocked
    const __hip_bfloat16* __restrict__ wb,   // [9][512][512] tap-major
    const float* __restrict__ demod,
    const float* __restrict__ noise,
    const float* __restrict__ bias,
    const float* __restrict__ nstr,
    float* __restrict__ out) {
    __shared__ __align__(16) char Xl[25344];     // 396 entries x 64 B
    __shared__ __align__(16) char Wl[6][8192];   // 2 banks x 3 taps x 8 KB

    const int t = threadIdx.x;
    const int bi = blockIdx.x;
    const int spat = bi & 127;            // same spat -> same bi%8 -> same XCD
    const int b = spat >> 4;
    const int h0 = (spat & 15) << 2;
    const int co0 = (bi >> 7) << 7;
    const int lane = t & 63;
    const int wv = t >> 6;
    const int wm = wv & 1, wn = wv >> 1;
    const int el = lane & 31;
    const int hk = lane >> 5;

    f32x16 acc[2][4];
#pragma unroll
    for (int i = 0; i < 2; ++i)
#pragma unroll
        for (int j = 0; j < 4; ++j)
#pragma unroll
            for (int k = 0; k < 16; ++k) acc[i][j][k] = 0.f;

    // ---- staging source pointers (rotation-swizzled) ----
    const char* xsb = (const char*)xs + (size_t)b * 4460544;
    const char* xsrc[7];
#pragma unroll
    for (int i = 0; i < 6; ++i) {
        int g = i * 256 + t;
        int e = g >> 2, s = g & 3;
        int gc = (s - (e >> 2)) & 3;
        int row = e / 66, col = e - row * 66;
        xsrc[i] = xsb + (size_t)((h0 + row) * 66 + col) * 64 + gc * 16;
    }
    {   // tail entries 384..395 (threads 0..47 only)
        int g = 1536 + t;
        int e = g >> 2, s = g & 3;
        int gc = (s - (e >> 2)) & 3;
        int row = e / 66, col = e - row * 66;
        xsrc[6] = xsb + (size_t)((h0 + row) * 66 + col) * 64 + gc * 16;
    }
    const char* wsrc[2];
#pragma unroll
    for (int i = 0; i < 2; ++i) {
        int g = i * 256 + t;
        int e = g >> 2, s = g & 3;
        int gc = (s - (e >> 2)) & 3;
        wsrc[i] = (const char*)wb + (size_t)(co0 + e) * 1024 + gc * 16;
    }
    const int wvoff = wv << 10;

    // ---- prologue: X(cb=0) + W phase 0 (taps 0-2 -> buffers 0-2) ----
#pragma unroll
    for (int i = 0; i < 6; ++i) gload_lds16(xsrc[i], Xl + i * 4096 + wvoff);
    if (t < 48) gload_lds16(xsrc[6], Xl + 24576);
#pragma unroll
    for (int tt = 0; tt < 3; ++tt)
#pragma unroll
        for (int i = 0; i < 2; ++i)
            gload_lds16(wsrc[i] + (size_t)tt * 524288,
                        Wl[tt] + i * 4096 + wvoff);
    sync_drain();

    int cboff = 0;
    for (int cb = 0; cb < 16; ++cb, cboff += 64) {
        const int ncboff = (cb < 15) ? cboff + 64 : cboff;  // cb15: dead dummy
#pragma unroll
        for (int p = 0; p < 3; ++p) {
            const int bank = ((cb + p) & 1) * 3;
            const int nbank = 3 - bank;
            // ---- prefetch phase p+1 (6 loads/wave) into the other bank ----
#pragma unroll
            for (int tt = 0; tt < 3; ++tt) {
                const size_t soff = (p < 2)
                    ? (size_t)(3 * (p + 1) + tt) * 524288 + cboff
                    : (size_t)tt * 524288 + ncboff;
                char* dst = Wl[nbank + tt] + wvoff;
#pragma unroll
                for (int i = 0; i < 2; ++i)
                    gload_lds16(wsrc[i] + soff, dst + i * 4096);
            }
            // ---- compute taps 3p..3p+2 (dh = p, dw = tt), barrier-free ----
#pragma unroll
            for (int tt = 0; tt < 3; ++tt) {
                const char* Wb = Wl[bank + tt];
#pragma unroll
                for (int ks = 0; ks < 2; ++ks) {
                    const int c = 2 * ks + hk;
                    s16x8 af[2], bfr[4];
#pragma unroll
                    for (int mi = 0; mi < 2; ++mi) {
                        int e = wm * 64 + mi * 32 + el;
                        af[mi] = *(const s16x8*)(Wb + e * 64 +
                                                 (((c + (e >> 2)) & 3) << 4));
                    }
#pragma unroll
                    for (int ni = 0; ni < 4; ++ni) {
                        int e = (2 * wn + (ni >> 1) + p) * 66 + tt +
                                (ni & 1) * 32 + el;
                        bfr[ni] = *(const s16x8*)(Xl + e * 64 +
                                                  (((c + (e >> 2)) & 3) << 4));
                    }
#pragma unroll
                    for (int mi = 0; mi < 2; ++mi)
#pragma unroll
                        for (int ni = 0; ni < 4; ++ni)
                            acc[mi][ni] =
                                __builtin_amdgcn_mfma_f32_32x32x16_bf16(
                                    af[mi], bfr[ni], acc[mi][ni], 0, 0, 0);
                }
            }
            // ---- phase barrier: drains phase p+1 loads (full-phase slack) ----
            sync_drain();
        }
        // ---- restage X (single buffer, between its own barrier pair) ----
        if (cb < 15) {
            const size_t xo = (size_t)(cb + 1) * 278784;
#pragma unroll
            for (int i = 0; i < 6; ++i)
                gload_lds16(xsrc[i] + xo, Xl + i * 4096 + wvoff);
            if (t < 48) gload_lds16(xsrc[6] + xo, Xl + 24576);
            sync_drain();
        }
    }

    // ---- epilogue: *demod + noise*strength + bias, leaky_relu(0.2)*sqrt(2) ----
    const float nsv = nstr[0];
    const float LR = 1.4142135623730951f;
#pragma unroll
    for (int mi = 0; mi < 2; ++mi) {
        float dm[16], bs[16];
#pragma unroll
        for (int rg = 0; rg < 16; ++rg) {
            int co = co0 + wm * 64 + mi * 32 + (rg & 3) + 8 * (rg >> 2) + 4 * hk;
            dm[rg] = demod[b * 512 + co];
            bs[rg] = bias[co];
        }
#pragma unroll
        for (int ni = 0; ni < 4; ++ni) {
            int h = h0 + 2 * wn + (ni >> 1);
            int w = (ni & 1) * 32 + el;
            float nz = nsv * noise[h * 64 + w];
#pragma unroll
            for (int rg = 0; rg < 16; ++rg) {
                int co = co0 + wm * 64 + mi * 32 + (rg & 3) + 8 * (rg >> 2) +
                         4 * hk;
                float v = acc[mi][ni][rg] * dm[rg] + nz + bs[rg];
                v = (v >= 0.f ? v : 0.2f * v) * LR;
                out[(((size_t)b * 512 + co) * 64 + h) * 64 + w] = v;
            }
        }
    }
}

// ---------------------------------------------------------------------------
extern "C" void kernel_launch(void* const* d_in, const int* in_sizes, int n_in,
                              void* d_out, int out_size, void* d_ws, size_t ws_size,
                              hipStream_t stream) {
    const float* x      = (const float*)d_in[0];
    const float* style  = (const float*)d_in[1];
    const float* noise  = (const float*)d_in[2];
    const float* weight = (const float*)d_in[3];
    const float* bias   = (const float*)d_in[4];
    const float* nstr   = (const float*)d_in[5];
    float* out = (float*)d_out;

    char* ws = (char*)d_ws;
    __hip_bfloat16* xs = (__hip_bfloat16*)ws;              // 35,684,352 B (blocked)
    __hip_bfloat16* wb = (__hip_bfloat16*)(ws + 35684352); //  4,718,592 B
    float* demod = (float*)(ws + 35684352 + 4718592);      //     16,384 B

    k_xprep<<<1024, 256, 0, stream>>>(x, style, xs);
    k_aux<<<2056, 256, 0, stream>>>(style, weight, xs, wb, demod);
    k_conv<<<512, 256, 0, stream>>>(xs, wb, demod, noise, bias, nstr, out);
}